// Round 6
// baseline (1192.830 us; speedup 1.0000x reference)
//
#include <hip/hip_runtime.h>

#define N_NODES 50000
#define N_EDGES 800000
#define K_BR    8
#define BCAP    131072           // per-bucket slot capacity (2^17); mean fill 100K, sigma ~300
#define MLP_SLOTS (K_BR * BCAP)  // 1,048,576

// ---------------- workspace layout (bytes) ----------------
// fbuf      : 1,048,576 rows x 64 B bf16 @ 0           (67,108,864)
// perm      : MLP_SLOTS ints             @ 67,108,864  (4,194,304)  [NOT memset: fill-guarded]
// slotLocal : E ints                     @ 71,303,168  (3,200,000)
// cnt(deg)  : N ints                     @ 74,503,168  (200,000)
// bucketCur : 8 ints (fill counts)       @ 74,703,168  (32)
// nodeStart : N ints                     @ 74,703,232  (200,000)
// total: 74,903,232  (< proven ws floor 109,473,920)

__device__ __forceinline__ int branch_idx(float dx, float dy) {
    return (dx > 0.0f ? 1 : 0) + (dy > 0.0f ? 2 : 0) +
           ((fabsf(dx) - fabsf(dy)) > 0.0f ? 4 : 0);
}

__device__ __forceinline__ unsigned int pk_bf16(float a, float b) {
    unsigned int ua = __float_as_uint(a), ub = __float_as_uint(b);
    ua += 0x7FFFu + ((ua >> 16) & 1u);   // round-to-nearest-even
    ub += 0x7FFFu + ((ub >> 16) & 1u);
    return (ua >> 16) | (ub & 0xFFFF0000u);
}

// ONE pass over edges: branch histogram + bucket scatter (perm) + CSR rank.
// 800000 = 3125 * 256 exactly -> no bounds check.
// After the grid completes, bucketCur[k] == total edges in bucket k.
__global__ void pass1_kernel(const int* __restrict__ ei, const float* __restrict__ pos,
                             int* __restrict__ cnt, int* __restrict__ slotLocal,
                             int* __restrict__ bucketCur, int* __restrict__ perm) {
    __shared__ int h[K_BR];
    __shared__ int base[K_BR];
    int t = threadIdx.x;
    if (t < K_BR) h[t] = 0;
    __syncthreads();
    int e = blockIdx.x * 256 + t;
    int s = ei[e], d = ei[N_EDGES + e];
    float2 ps = ((const float2*)pos)[s];
    float2 pd = ((const float2*)pos)[d];
    int k = branch_idx(ps.x - pd.x, ps.y - pd.y);
    int rank = atomicAdd(&h[k], 1);
    slotLocal[e] = atomicAdd(&cnt[d], 1);
    __syncthreads();
    if (t < K_BR) base[t] = (h[t] > 0) ? atomicAdd(&bucketCur[t], h[t]) : 0;
    __syncthreads();
    perm[(k << 17) + base[k] + rank] = e;
}

// single-block exclusive scan of cnt[N] -> nodeStart[N] (replaces 3 kernels)
__global__ void __launch_bounds__(1024) scan_kernel(const int* __restrict__ cnt,
                                                    int* __restrict__ nodeStart) {
    __shared__ int s[1024];
    const int CH = 49;  // 1024*49 = 50176 >= 50000
    int t = threadIdx.x;
    int base = t * CH;
    int sum = 0;
#pragma unroll 1
    for (int j = 0; j < CH; ++j) {
        int i = base + j;
        sum += (i < N_NODES) ? cnt[i] : 0;
    }
    s[t] = sum;
    __syncthreads();
    for (int off = 1; off < 1024; off <<= 1) {
        int tmp = (t >= off) ? s[t - off] : 0;
        __syncthreads();
        s[t] += tmp;
        __syncthreads();
    }
    int run = s[t] - sum;  // exclusive prefix of this chunk
#pragma unroll 1
    for (int j = 0; j < CH; ++j) {
        int i = base + j;
        if (i < N_NODES) {
            int c = cnt[i];
            nodeStart[i] = run;
            run += c;
        }
    }
}

// 2 edges per lane: each weight s_load feeds 2 FMAs (halves scalar-wait/FLOP).
__global__ void __launch_bounds__(256) mlp_kernel(
    const int* __restrict__ perm, const int* __restrict__ ei,
    const float* __restrict__ x, const float* __restrict__ ea,
    const float* __restrict__ ew,
    const float* __restrict__ W1, const float* __restrict__ b1,
    const float* __restrict__ W2, const float* __restrict__ b2,
    const int* __restrict__ nodeStart, const int* __restrict__ slotLocal,
    const int* __restrict__ bucketFill,
    unsigned short* __restrict__ fbuf) {
    int t = blockIdx.x * 256 + threadIdx.x;   // handles slots 2t, 2t+1
    int s0 = 2 * t;
    // wave-uniform bucket id + fill count -> s_load weights (R4 lesson: must be
    // readfirstlane-derived or weight loads become per-lane global_loads).
    int u  = __builtin_amdgcn_readfirstlane(s0);
    int k  = u >> 17;
    int fill = bucketFill[k];
    if ((u & (BCAP - 1)) >= fill) return;     // whole wave past bucket fill
    int rel0 = s0 & (BCAP - 1);
    bool v0 = rel0 < fill, v1 = rel0 + 1 < fill;
    int kbase = k << 17;
    int e0 = perm[kbase + min(rel0, fill - 1)];       // clamped: perm pad is garbage
    int e1 = perm[kbase + min(rel0 + 1, fill - 1)];

    int sa = ei[e0], da = ei[N_EDGES + e0];
    int sb = ei[e1], db = ei[N_EDGES + e1];

    float m0[36], m1[36];
    const float4* xja = (const float4*)(x + 32 * (size_t)sa);
    const float4* xia = (const float4*)(x + 32 * (size_t)da);
    const float4* xjb = (const float4*)(x + 32 * (size_t)sb);
    const float4* xib = (const float4*)(x + 32 * (size_t)db);
#pragma unroll
    for (int q = 0; q < 8; ++q) {
        float4 a0 = xja[q], b0 = xia[q];
        m0[4 * q + 0] = a0.x - b0.x; m0[4 * q + 1] = a0.y - b0.y;
        m0[4 * q + 2] = a0.z - b0.z; m0[4 * q + 3] = a0.w - b0.w;
        float4 a1 = xjb[q], b1v = xib[q];
        m1[4 * q + 0] = a1.x - b1v.x; m1[4 * q + 1] = a1.y - b1v.y;
        m1[4 * q + 2] = a1.z - b1v.z; m1[4 * q + 3] = a1.w - b1v.w;
    }
    float4 ea0 = ((const float4*)ea)[e0];
    float4 ea1 = ((const float4*)ea)[e1];
    m0[32] = ea0.x; m0[33] = ea0.y; m0[34] = ea0.z; m0[35] = ea0.w;
    m1[32] = ea1.x; m1[33] = ea1.y; m1[34] = ea1.z; m1[35] = ea1.w;
    float w0 = ew[e0], w1v = ew[e1];
    int slot0 = nodeStart[da] + slotLocal[e0];
    int slot1 = nodeStart[db] + slotLocal[e1];

    // Layer 1: c-outer / o-inner, original [k][c][o] layout, shared s_loads.
    const float* w1p = W1 + k * (36 * 32);
    const float* bb1 = b1 + k * 32;
    float a0[32], a1[32];
#pragma unroll
    for (int o = 0; o < 32; ++o) { float b = bb1[o]; a0[o] = b; a1[o] = b; }
#pragma unroll
    for (int c = 0; c < 36; ++c) {
        float mc0 = m0[c], mc1 = m1[c];
#pragma unroll
        for (int o = 0; o < 32; ++o) {
            float wv = w1p[c * 32 + o];
            a0[o] = fmaf(mc0, wv, a0[o]);
            a1[o] = fmaf(mc1, wv, a1[o]);
        }
    }
#pragma unroll
    for (int o = 0; o < 32; ++o) { a0[o] = fmaxf(a0[o], 0.0f); a1[o] = fmaxf(a1[o], 0.0f); }

    // Layer 2: o-outer / g-inner, original [k][o][g] layout, shared s_loads.
    const float* w2p = W2 + k * (32 * 32);
    const float* bb2 = b2 + k * 32;
    float c0[32], c1[32];
#pragma unroll
    for (int g = 0; g < 32; ++g) { float b = bb2[g]; c0[g] = b; c1[g] = b; }
#pragma unroll
    for (int o = 0; o < 32; ++o) {
        float h0 = a0[o], h1 = a1[o];
#pragma unroll
        for (int g = 0; g < 32; ++g) {
            float wv = w2p[o * 32 + g];
            c0[g] = fmaf(h0, wv, c0[g]);
            c1[g] = fmaf(h1, wv, c1[g]);
        }
    }

    uint4* frow0 = (uint4*)(fbuf + 32 * (size_t)slot0);
    uint4* frow1 = (uint4*)(fbuf + 32 * (size_t)slot1);
#pragma unroll
    for (int q = 0; q < 4; ++q) {
        uint4 r;
        r.x = pk_bf16(fmaxf(c0[8 * q + 0], 0.0f) * w0, fmaxf(c0[8 * q + 1], 0.0f) * w0);
        r.y = pk_bf16(fmaxf(c0[8 * q + 2], 0.0f) * w0, fmaxf(c0[8 * q + 3], 0.0f) * w0);
        r.z = pk_bf16(fmaxf(c0[8 * q + 4], 0.0f) * w0, fmaxf(c0[8 * q + 5], 0.0f) * w0);
        r.w = pk_bf16(fmaxf(c0[8 * q + 6], 0.0f) * w0, fmaxf(c0[8 * q + 7], 0.0f) * w0);
        if (v0) frow0[q] = r;
    }
#pragma unroll
    for (int q = 0; q < 4; ++q) {
        uint4 r;
        r.x = pk_bf16(fmaxf(c1[8 * q + 0], 0.0f) * w1v, fmaxf(c1[8 * q + 1], 0.0f) * w1v);
        r.y = pk_bf16(fmaxf(c1[8 * q + 2], 0.0f) * w1v, fmaxf(c1[8 * q + 3], 0.0f) * w1v);
        r.z = pk_bf16(fmaxf(c1[8 * q + 4], 0.0f) * w1v, fmaxf(c1[8 * q + 5], 0.0f) * w1v);
        r.w = pk_bf16(fmaxf(c1[8 * q + 6], 0.0f) * w1v, fmaxf(c1[8 * q + 7], 0.0f) * w1v);
        if (v1) frow1[q] = r;
    }
}

__global__ void agg_kernel(const unsigned short* __restrict__ fbuf,
                           const int* __restrict__ nodeStart, const int* __restrict__ deg,
                           const float* __restrict__ x, const float* __restrict__ Wr,
                           const float* __restrict__ br, float* __restrict__ out) {
    int t = blockIdx.x * blockDim.x + threadIdx.x;
    if (t >= N_NODES * 32) return;
    int n = t >> 5, o = t & 31;
    int st = nodeStart[n], dg = deg[n];
    float acc = 0.0f;
    for (int j = 0; j < dg; ++j) {
        unsigned int u = fbuf[(size_t)(st + j) * 32 + o];  // CSR-contiguous stream
        acc += __uint_as_float(u << 16);
    }
    float inv = 1.0f / (float)max(dg, 1);
    acc = acc * inv + br[o];
    const float* xr = x + 32 * (size_t)n;
#pragma unroll
    for (int c = 0; c < 32; ++c) acc = fmaf(xr[c], Wr[c * 32 + o], acc);
    out[t] = acc;
}

extern "C" void kernel_launch(void* const* d_in, const int* in_sizes, int n_in,
                              void* d_out, int out_size, void* d_ws, size_t ws_size,
                              hipStream_t stream) {
    const float* x   = (const float*)d_in[0];
    const float* pos = (const float*)d_in[1];
    const int*   ei  = (const int*)d_in[2];
    const float* ea  = (const float*)d_in[3];
    const float* ew  = (const float*)d_in[4];
    const float* W1  = (const float*)d_in[5];
    const float* b1  = (const float*)d_in[6];
    const float* W2  = (const float*)d_in[7];
    const float* b2  = (const float*)d_in[8];
    const float* Wr  = (const float*)d_in[9];
    const float* br  = (const float*)d_in[10];
    float* out = (float*)d_out;

    char* ws = (char*)d_ws;
    unsigned short* fbuf = (unsigned short*)(ws + 0);
    int* perm      = (int*)(ws + 67108864);
    int* slotLocal = (int*)(ws + 71303168);
    int* cnt       = (int*)(ws + 74503168);
    int* bucketCur = (int*)(ws + 74703168);
    int* nodeStart = (int*)(ws + 74703232);

    hipMemsetAsync(cnt, 0, 200032, stream);  // cnt + bucketCur (contiguous)

    pass1_kernel<<<N_EDGES / 256, 256, 0, stream>>>(ei, pos, cnt, slotLocal, bucketCur, perm);
    scan_kernel<<<1, 1024, 0, stream>>>(cnt, nodeStart);
    mlp_kernel<<<MLP_SLOTS / 2 / 256, 256, 0, stream>>>(perm, ei, x, ea, ew,
                                                        W1, b1, W2, b2,
                                                        nodeStart, slotLocal, bucketCur, fbuf);
    agg_kernel<<<(N_NODES * 32 + 255) / 256, 256, 0, stream>>>(fbuf, nodeStart, cnt,
                                                               x, Wr, br, out);
}

// Round 7
// 339.848 us; speedup vs baseline: 3.5099x; 3.5099x over previous
//
#include <hip/hip_runtime.h>

#define N_NODES 50000
#define N_EDGES 800000
#define K_BR    8
#define BCAP    131072           // per-bucket slot capacity (2^17); mean fill 100K, sigma ~300
#define MLP_SLOTS (K_BR * BCAP)  // 1,048,576

// ---------------- workspace layout (bytes) ----------------
// fbuf      : 1,048,576 rows x 64 B bf16 @ 0           (67,108,864)
// perm      : MLP_SLOTS ints             @ 67,108,864  (4,194,304)  [NOT memset: fill-guarded]
// slotLocal : E ints                     @ 71,303,168  (3,200,000)
// cnt(deg)  : N ints                     @ 74,503,168  (200,000)
// bucketCur : 8 ints (fill counts)       @ 74,703,168  (32)
// nodeStart : N ints                     @ 74,703,232  (200,000)
// total: 74,903,232  (< proven ws floor 109,473,920)

__device__ __forceinline__ int branch_idx(float dx, float dy) {
    return (dx > 0.0f ? 1 : 0) + (dy > 0.0f ? 2 : 0) +
           ((fabsf(dx) - fabsf(dy)) > 0.0f ? 4 : 0);
}

__device__ __forceinline__ unsigned int pk_bf16(float a, float b) {
    unsigned int ua = __float_as_uint(a), ub = __float_as_uint(b);
    ua += 0x7FFFu + ((ua >> 16) & 1u);   // round-to-nearest-even
    ub += 0x7FFFu + ((ub >> 16) & 1u);
    return (ua >> 16) | (ub & 0xFFFF0000u);
}

// ONE pass over edges: branch histogram + bucket scatter (perm) + CSR rank.
// 800000 = 3125 * 256 exactly -> no bounds check.
// After the grid completes, bucketCur[k] == total edges in bucket k.
__global__ void pass1_kernel(const int* __restrict__ ei, const float* __restrict__ pos,
                             int* __restrict__ cnt, int* __restrict__ slotLocal,
                             int* __restrict__ bucketCur, int* __restrict__ perm) {
    __shared__ int h[K_BR];
    __shared__ int base[K_BR];
    int t = threadIdx.x;
    if (t < K_BR) h[t] = 0;
    __syncthreads();
    int e = blockIdx.x * 256 + t;
    int s = ei[e], d = ei[N_EDGES + e];
    float2 ps = ((const float2*)pos)[s];
    float2 pd = ((const float2*)pos)[d];
    int k = branch_idx(ps.x - pd.x, ps.y - pd.y);
    int rank = atomicAdd(&h[k], 1);
    slotLocal[e] = atomicAdd(&cnt[d], 1);
    __syncthreads();
    if (t < K_BR) base[t] = (h[t] > 0) ? atomicAdd(&bucketCur[t], h[t]) : 0;
    __syncthreads();
    perm[(k << 17) + base[k] + rank] = e;
}

// single-block exclusive scan of cnt[N] -> nodeStart[N]
__global__ void __launch_bounds__(1024) scan_kernel(const int* __restrict__ cnt,
                                                    int* __restrict__ nodeStart) {
    __shared__ int s[1024];
    const int CH = 49;  // 1024*49 = 50176 >= 50000
    int t = threadIdx.x;
    int base = t * CH;
    int sum = 0;
#pragma unroll 1
    for (int j = 0; j < CH; ++j) {
        int i = base + j;
        sum += (i < N_NODES) ? cnt[i] : 0;
    }
    s[t] = sum;
    __syncthreads();
    for (int off = 1; off < 1024; off <<= 1) {
        int tmp = (t >= off) ? s[t - off] : 0;
        __syncthreads();
        s[t] += tmp;
        __syncthreads();
    }
    int run = s[t] - sum;  // exclusive prefix of this chunk
#pragma unroll 1
    for (int j = 0; j < CH; ++j) {
        int i = base + j;
        if (i < N_NODES) {
            int c = cnt[i];
            nodeStart[i] = run;
            run += c;
        }
    }
}

// R5-proven 1-edge-per-lane MLP (VGPR ~40). R6 lesson: 2 edges/lane spills
// (VGPR 116, 11x slower) — scale across waves, not per-lane state.
__global__ void __launch_bounds__(256) mlp_kernel(
    const int* __restrict__ perm, const int* __restrict__ ei,
    const float* __restrict__ x, const float* __restrict__ ea,
    const float* __restrict__ ew,
    const float* __restrict__ W1, const float* __restrict__ b1,
    const float* __restrict__ W2, const float* __restrict__ b2,
    const int* __restrict__ nodeStart, const int* __restrict__ slotLocal,
    const int* __restrict__ bucketFill,
    unsigned short* __restrict__ fbuf) {
    int t = blockIdx.x * 256 + threadIdx.x;
    // wave-uniform bucket id + fill count (R4 lesson: must be readfirstlane-
    // derived or the 2304 weight loads become per-lane global_loads).
    int u = __builtin_amdgcn_readfirstlane(t);
    int k = u >> 17;
    int fill = bucketFill[k];
    if ((u & (BCAP - 1)) >= fill) return;   // whole wave past bucket fill
    int rel = t & (BCAP - 1);
    bool valid = rel < fill;
    int e = perm[(k << 17) + min(rel, fill - 1)];  // clamp: pad slots are garbage

    int s = ei[e];
    int d = ei[N_EDGES + e];

    float m[36];
    const float4* xj = (const float4*)(x + 32 * (size_t)s);
    const float4* xi = (const float4*)(x + 32 * (size_t)d);
#pragma unroll
    for (int q = 0; q < 8; ++q) {
        float4 a = xj[q], b = xi[q];
        m[4 * q + 0] = a.x - b.x;
        m[4 * q + 1] = a.y - b.y;
        m[4 * q + 2] = a.z - b.z;
        m[4 * q + 3] = a.w - b.w;
    }
    float4 eav = ((const float4*)ea)[e];
    m[32] = eav.x; m[33] = eav.y; m[34] = eav.z; m[35] = eav.w;
    float w = ew[e];
    int slot = valid ? (nodeStart[d] + slotLocal[e]) : 0;

    // Layer 1: c-outer / o-inner -> weights stream contiguously in the
    // ORIGINAL [k][c][o] layout (no transpose), sequential s_load bursts.
    const float* w1  = W1 + k * (36 * 32);
    const float* bb1 = b1 + k * 32;
    float acc[32];
#pragma unroll
    for (int o = 0; o < 32; ++o) acc[o] = bb1[o];
#pragma unroll
    for (int c = 0; c < 36; ++c) {
        float mc = m[c];
#pragma unroll
        for (int o = 0; o < 32; ++o) acc[o] = fmaf(mc, w1[c * 32 + o], acc[o]);
    }
#pragma unroll
    for (int o = 0; o < 32; ++o) acc[o] = fmaxf(acc[o], 0.0f);

    // Layer 2: o-outer / g-inner, original [k][o][g] layout.
    const float* w2  = W2 + k * (32 * 32);
    const float* bb2 = b2 + k * 32;
    float acc2[32];
#pragma unroll
    for (int g = 0; g < 32; ++g) acc2[g] = bb2[g];
#pragma unroll
    for (int o = 0; o < 32; ++o) {
        float ho = acc[o];
#pragma unroll
        for (int g = 0; g < 32; ++g) acc2[g] = fmaf(ho, w2[o * 32 + g], acc2[g]);
    }

    // store bf16 row directly at the CSR slot -> agg reads fully streaming
    uint4* frow = (uint4*)(fbuf + 32 * (size_t)slot);
#pragma unroll
    for (int q = 0; q < 4; ++q) {
        uint4 r;
        r.x = pk_bf16(fmaxf(acc2[8 * q + 0], 0.0f) * w, fmaxf(acc2[8 * q + 1], 0.0f) * w);
        r.y = pk_bf16(fmaxf(acc2[8 * q + 2], 0.0f) * w, fmaxf(acc2[8 * q + 3], 0.0f) * w);
        r.z = pk_bf16(fmaxf(acc2[8 * q + 4], 0.0f) * w, fmaxf(acc2[8 * q + 5], 0.0f) * w);
        r.w = pk_bf16(fmaxf(acc2[8 * q + 6], 0.0f) * w, fmaxf(acc2[8 * q + 7], 0.0f) * w);
        if (valid) frow[q] = r;
    }
}

// 2 channels per thread: uint read = 2 bf16 -> 256B/wave-inst fbuf streaming.
__global__ void agg_kernel(const unsigned short* __restrict__ fbuf,
                           const int* __restrict__ nodeStart, const int* __restrict__ deg,
                           const float* __restrict__ x, const float* __restrict__ Wr,
                           const float* __restrict__ br, float* __restrict__ out) {
    int t = blockIdx.x * blockDim.x + threadIdx.x;
    if (t >= N_NODES * 16) return;
    int n = t >> 4, hc = t & 15;          // channels 2*hc, 2*hc+1
    int st = nodeStart[n], dg = deg[n];
    const unsigned int* fb = (const unsigned int*)fbuf;
    float acc0 = 0.0f, acc1 = 0.0f;
    for (int j = 0; j < dg; ++j) {
        unsigned int u = fb[(size_t)(st + j) * 16 + hc];  // CSR-contiguous stream
        acc0 += __uint_as_float(u << 16);
        acc1 += __uint_as_float(u & 0xFFFF0000u);
    }
    float inv = 1.0f / (float)max(dg, 1);
    int o = hc * 2;
    acc0 = acc0 * inv + br[o];
    acc1 = acc1 * inv + br[o + 1];
    const float* xr = x + 32 * (size_t)n;
#pragma unroll
    for (int c = 0; c < 32; ++c) {
        float xv = xr[c];
        acc0 = fmaf(xv, Wr[c * 32 + o], acc0);
        acc1 = fmaf(xv, Wr[c * 32 + o + 1], acc1);
    }
    float2* o2 = (float2*)(out + 32 * (size_t)n + o);
    *o2 = make_float2(acc0, acc1);
}

extern "C" void kernel_launch(void* const* d_in, const int* in_sizes, int n_in,
                              void* d_out, int out_size, void* d_ws, size_t ws_size,
                              hipStream_t stream) {
    const float* x   = (const float*)d_in[0];
    const float* pos = (const float*)d_in[1];
    const int*   ei  = (const int*)d_in[2];
    const float* ea  = (const float*)d_in[3];
    const float* ew  = (const float*)d_in[4];
    const float* W1  = (const float*)d_in[5];
    const float* b1  = (const float*)d_in[6];
    const float* W2  = (const float*)d_in[7];
    const float* b2  = (const float*)d_in[8];
    const float* Wr  = (const float*)d_in[9];
    const float* br  = (const float*)d_in[10];
    float* out = (float*)d_out;

    char* ws = (char*)d_ws;
    unsigned short* fbuf = (unsigned short*)(ws + 0);
    int* perm      = (int*)(ws + 67108864);
    int* slotLocal = (int*)(ws + 71303168);
    int* cnt       = (int*)(ws + 74503168);
    int* bucketCur = (int*)(ws + 74703168);
    int* nodeStart = (int*)(ws + 74703232);

    hipMemsetAsync(cnt, 0, 200032, stream);  // cnt + bucketCur (contiguous)

    pass1_kernel<<<N_EDGES / 256, 256, 0, stream>>>(ei, pos, cnt, slotLocal, bucketCur, perm);
    scan_kernel<<<1, 1024, 0, stream>>>(cnt, nodeStart);
    mlp_kernel<<<MLP_SLOTS / 256, 256, 0, stream>>>(perm, ei, x, ea, ew,
                                                    W1, b1, W2, b2,
                                                    nodeStart, slotLocal, bucketCur, fbuf);
    agg_kernel<<<(N_NODES * 16 + 255) / 256, 256, 0, stream>>>(fbuf, nodeStart, cnt,
                                                               x, Wr, br, out);
}

// Round 8
// 254.949 us; speedup vs baseline: 4.6787x; 1.3330x over previous
//
#include <hip/hip_runtime.h>

#define N_NODES 50000
#define N_EDGES 800000
#define K_BR    8
#define BCAP    131072           // per-bucket slot capacity (2^17); mean fill 100K, sigma ~300
#define MLP_SLOTS (K_BR * BCAP)  // 1,048,576
#define SCAN_BLOCKS 196          // ceil(50000/256)

// ---------------- workspace layout (bytes) ----------------
// fbuf      : 1,048,576 rows x 64 B bf16 @ 0           (67,108,864)
// perm      : MLP_SLOTS ints             @ 67,108,864  (4,194,304)  [NOT memset: fill-guarded]
// slotLocal : E ints                     @ 71,303,168  (3,200,000)
// cnt(deg)  : N ints                     @ 74,503,168  (200,000)
// bucketCur : 8 ints (fill counts)       @ 74,703,168  (32)
// nodeStart : N ints                     @ 74,703,232  (200,000)
// blockSums : 256 ints                   @ 74,903,232  (1,024)
// blockOffs : 256 ints                   @ 74,904,256  (1,024)
// total: 74,905,280  (< proven ws floor 109,473,920)

__device__ __forceinline__ int branch_idx(float dx, float dy) {
    return (dx > 0.0f ? 1 : 0) + (dy > 0.0f ? 2 : 0) +
           ((fabsf(dx) - fabsf(dy)) > 0.0f ? 4 : 0);
}

__device__ __forceinline__ unsigned int pk_bf16(float a, float b) {
    unsigned int ua = __float_as_uint(a), ub = __float_as_uint(b);
    ua += 0x7FFFu + ((ua >> 16) & 1u);   // round-to-nearest-even
    ub += 0x7FFFu + ((ub >> 16) & 1u);
    return (ua >> 16) | (ub & 0xFFFF0000u);
}

// ONE pass over edges: branch histogram + bucket scatter (perm) + CSR rank.
// 800000 = 3125 * 256 exactly -> no bounds check.
// After the grid completes, bucketCur[k] == total edges in bucket k.
__global__ void pass1_kernel(const int* __restrict__ ei, const float* __restrict__ pos,
                             int* __restrict__ cnt, int* __restrict__ slotLocal,
                             int* __restrict__ bucketCur, int* __restrict__ perm) {
    __shared__ int h[K_BR];
    __shared__ int base[K_BR];
    int t = threadIdx.x;
    if (t < K_BR) h[t] = 0;
    __syncthreads();
    int e = blockIdx.x * 256 + t;
    int s = ei[e], d = ei[N_EDGES + e];
    float2 ps = ((const float2*)pos)[s];
    float2 pd = ((const float2*)pos)[d];
    int k = branch_idx(ps.x - pd.x, ps.y - pd.y);
    int rank = atomicAdd(&h[k], 1);
    slotLocal[e] = atomicAdd(&cnt[d], 1);
    __syncthreads();
    if (t < K_BR) base[t] = (h[t] > 0) ? atomicAdd(&bucketCur[t], h[t]) : 0;
    __syncthreads();
    perm[(k << 17) + base[k] + rank] = e;
}

// ---- parallel hierarchical exclusive scan of cnt[N] -> nodeStart[N] ----
// (R7 lesson: single-block fused scan = 95us latency-bound; this 3-kernel
//  version is ~5us total across 196 blocks.)
__global__ void scanA_kernel(const int* __restrict__ cnt, int* __restrict__ nodeStart,
                             int* __restrict__ blockSums) {
    __shared__ int s[256];
    int t = threadIdx.x;
    int i = blockIdx.x * 256 + t;
    int v = (i < N_NODES) ? cnt[i] : 0;
    s[t] = v;
    __syncthreads();
#pragma unroll
    for (int off = 1; off < 256; off <<= 1) {
        int tmp = (t >= off) ? s[t - off] : 0;
        __syncthreads();
        s[t] += tmp;
        __syncthreads();
    }
    if (i < N_NODES) nodeStart[i] = s[t] - v;  // exclusive
    if (t == 255) blockSums[blockIdx.x] = s[255];
}

__global__ void scanB_kernel(const int* __restrict__ blockSums, int* __restrict__ blockOffs) {
    __shared__ int s[256];
    int t = threadIdx.x;
    int v = (t < SCAN_BLOCKS) ? blockSums[t] : 0;
    s[t] = v;
    __syncthreads();
#pragma unroll
    for (int off = 1; off < 256; off <<= 1) {
        int tmp = (t >= off) ? s[t - off] : 0;
        __syncthreads();
        s[t] += tmp;
        __syncthreads();
    }
    blockOffs[t] = s[t] - v;
}

__global__ void scanC_kernel(int* __restrict__ nodeStart, const int* __restrict__ blockOffs) {
    int i = blockIdx.x * 256 + threadIdx.x;
    if (i < N_NODES) nodeStart[i] += blockOffs[blockIdx.x];
}

// R5-proven 1-edge-per-lane MLP (VGPR ~40). R6 lesson: 2 edges/lane spills
// (VGPR 116, 11x slower) — scale across waves, not per-lane state.
__global__ void __launch_bounds__(256) mlp_kernel(
    const int* __restrict__ perm, const int* __restrict__ ei,
    const float* __restrict__ x, const float* __restrict__ ea,
    const float* __restrict__ ew,
    const float* __restrict__ W1, const float* __restrict__ b1,
    const float* __restrict__ W2, const float* __restrict__ b2,
    const int* __restrict__ nodeStart, const int* __restrict__ slotLocal,
    const int* __restrict__ bucketFill,
    unsigned short* __restrict__ fbuf) {
    int t = blockIdx.x * 256 + threadIdx.x;
    // wave-uniform bucket id + fill count (R4 lesson: must be readfirstlane-
    // derived or the 2304 weight loads become per-lane global_loads).
    int u = __builtin_amdgcn_readfirstlane(t);
    int k = u >> 17;
    int fill = bucketFill[k];
    if ((u & (BCAP - 1)) >= fill) return;   // whole wave past bucket fill
    int rel = t & (BCAP - 1);
    bool valid = rel < fill;
    int e = perm[(k << 17) + min(rel, fill - 1)];  // clamp: pad slots are garbage

    int s = ei[e];
    int d = ei[N_EDGES + e];

    float m[36];
    const float4* xj = (const float4*)(x + 32 * (size_t)s);
    const float4* xi = (const float4*)(x + 32 * (size_t)d);
#pragma unroll
    for (int q = 0; q < 8; ++q) {
        float4 a = xj[q], b = xi[q];
        m[4 * q + 0] = a.x - b.x;
        m[4 * q + 1] = a.y - b.y;
        m[4 * q + 2] = a.z - b.z;
        m[4 * q + 3] = a.w - b.w;
    }
    float4 eav = ((const float4*)ea)[e];
    m[32] = eav.x; m[33] = eav.y; m[34] = eav.z; m[35] = eav.w;
    float w = ew[e];
    int slot = valid ? (nodeStart[d] + slotLocal[e]) : 0;

    // Layer 1: c-outer / o-inner -> weights stream contiguously in the
    // ORIGINAL [k][c][o] layout (no transpose), sequential s_load bursts.
    const float* w1  = W1 + k * (36 * 32);
    const float* bb1 = b1 + k * 32;
    float acc[32];
#pragma unroll
    for (int o = 0; o < 32; ++o) acc[o] = bb1[o];
#pragma unroll
    for (int c = 0; c < 36; ++c) {
        float mc = m[c];
#pragma unroll
        for (int o = 0; o < 32; ++o) acc[o] = fmaf(mc, w1[c * 32 + o], acc[o]);
    }
#pragma unroll
    for (int o = 0; o < 32; ++o) acc[o] = fmaxf(acc[o], 0.0f);

    // Layer 2: o-outer / g-inner, original [k][o][g] layout.
    const float* w2  = W2 + k * (32 * 32);
    const float* bb2 = b2 + k * 32;
    float acc2[32];
#pragma unroll
    for (int g = 0; g < 32; ++g) acc2[g] = bb2[g];
#pragma unroll
    for (int o = 0; o < 32; ++o) {
        float ho = acc[o];
#pragma unroll
        for (int g = 0; g < 32; ++g) acc2[g] = fmaf(ho, w2[o * 32 + g], acc2[g]);
    }

    // store bf16 row directly at the CSR slot -> agg reads fully streaming
    uint4* frow = (uint4*)(fbuf + 32 * (size_t)slot);
#pragma unroll
    for (int q = 0; q < 4; ++q) {
        uint4 r;
        r.x = pk_bf16(fmaxf(acc2[8 * q + 0], 0.0f) * w, fmaxf(acc2[8 * q + 1], 0.0f) * w);
        r.y = pk_bf16(fmaxf(acc2[8 * q + 2], 0.0f) * w, fmaxf(acc2[8 * q + 3], 0.0f) * w);
        r.z = pk_bf16(fmaxf(acc2[8 * q + 4], 0.0f) * w, fmaxf(acc2[8 * q + 5], 0.0f) * w);
        r.w = pk_bf16(fmaxf(acc2[8 * q + 6], 0.0f) * w, fmaxf(acc2[8 * q + 7], 0.0f) * w);
        if (valid) frow[q] = r;
    }
}

// 2 channels per thread: uint read = 2 bf16 -> 256B/wave-inst fbuf streaming.
__global__ void agg_kernel(const unsigned short* __restrict__ fbuf,
                           const int* __restrict__ nodeStart, const int* __restrict__ deg,
                           const float* __restrict__ x, const float* __restrict__ Wr,
                           const float* __restrict__ br, float* __restrict__ out) {
    int t = blockIdx.x * blockDim.x + threadIdx.x;
    if (t >= N_NODES * 16) return;
    int n = t >> 4, hc = t & 15;          // channels 2*hc, 2*hc+1
    int st = nodeStart[n], dg = deg[n];
    const unsigned int* fb = (const unsigned int*)fbuf;
    float acc0 = 0.0f, acc1 = 0.0f;
    for (int j = 0; j < dg; ++j) {
        unsigned int u = fb[(size_t)(st + j) * 16 + hc];  // CSR-contiguous stream
        acc0 += __uint_as_float(u << 16);
        acc1 += __uint_as_float(u & 0xFFFF0000u);
    }
    float inv = 1.0f / (float)max(dg, 1);
    int o = hc * 2;
    acc0 = acc0 * inv + br[o];
    acc1 = acc1 * inv + br[o + 1];
    const float* xr = x + 32 * (size_t)n;
#pragma unroll
    for (int c = 0; c < 32; ++c) {
        float xv = xr[c];
        acc0 = fmaf(xv, Wr[c * 32 + o], acc0);
        acc1 = fmaf(xv, Wr[c * 32 + o + 1], acc1);
    }
    float2* o2 = (float2*)(out + 32 * (size_t)n + o);
    *o2 = make_float2(acc0, acc1);
}

extern "C" void kernel_launch(void* const* d_in, const int* in_sizes, int n_in,
                              void* d_out, int out_size, void* d_ws, size_t ws_size,
                              hipStream_t stream) {
    const float* x   = (const float*)d_in[0];
    const float* pos = (const float*)d_in[1];
    const int*   ei  = (const int*)d_in[2];
    const float* ea  = (const float*)d_in[3];
    const float* ew  = (const float*)d_in[4];
    const float* W1  = (const float*)d_in[5];
    const float* b1  = (const float*)d_in[6];
    const float* W2  = (const float*)d_in[7];
    const float* b2  = (const float*)d_in[8];
    const float* Wr  = (const float*)d_in[9];
    const float* br  = (const float*)d_in[10];
    float* out = (float*)d_out;

    char* ws = (char*)d_ws;
    unsigned short* fbuf = (unsigned short*)(ws + 0);
    int* perm      = (int*)(ws + 67108864);
    int* slotLocal = (int*)(ws + 71303168);
    int* cnt       = (int*)(ws + 74503168);
    int* bucketCur = (int*)(ws + 74703168);
    int* nodeStart = (int*)(ws + 74703232);
    int* blockSums = (int*)(ws + 74903232);
    int* blockOffs = (int*)(ws + 74904256);

    hipMemsetAsync(cnt, 0, 200032, stream);  // cnt + bucketCur (contiguous)

    pass1_kernel<<<N_EDGES / 256, 256, 0, stream>>>(ei, pos, cnt, slotLocal, bucketCur, perm);
    scanA_kernel<<<SCAN_BLOCKS, 256, 0, stream>>>(cnt, nodeStart, blockSums);
    scanB_kernel<<<1, 256, 0, stream>>>(blockSums, blockOffs);
    scanC_kernel<<<SCAN_BLOCKS, 256, 0, stream>>>(nodeStart, blockOffs);
    mlp_kernel<<<MLP_SLOTS / 256, 256, 0, stream>>>(perm, ei, x, ea, ew,
                                                    W1, b1, W2, b2,
                                                    nodeStart, slotLocal, bucketCur, fbuf);
    agg_kernel<<<(N_NODES * 16 + 255) / 256, 256, 0, stream>>>(fbuf, nodeStart, cnt,
                                                               x, Wr, br, out);
}